// Round 5
// baseline (829.678 us; speedup 1.0000x reference)
//
#include <hip/hip_runtime.h>

// Row-wise sparsemax over 4096 x 32000 fp32.
// R4: persistent-block cross-row software pipeline.
//  - grid = 256 blocks (1 per CU), 1024 threads, each block owns 16 rows.
//  - Row register-resident at VPT=8 (32 VGPRs); TWO row buffers va/vb
//    (64 data VGPRs, fits the 128-VGPR cap of __launch_bounds__(1024,4)).
//  - While row r runs reduce/gather/solve/store, row r+1's nt loads are in
//    flight (compiler emits counted vmcnt, prefetch survives the barriers)
//    -> the per-row serial phases no longer idle the memory pipe.
//  - LDS candidate list is parity double-buffered so the 2-barrier/row
//    structure stays race-free (init of parity p never overlaps the
//    redundant per-wave solve still reading parity 1-p).
//  - Row loop unrolled by 2 so all register-buffer indexing is static
//    (runtime-indexed register arrays go to scratch).
// Traffic floor unchanged: 1.05 GB one-pass = 166 us @ 6.3 TB/s.

#define NCOL  32000
#define NV4   8000         // NCOL / 4
#define NT    1024
#define VPT   8            // float4 per thread per row buffer
#define NWAVE 16           // NT / 64
#define CAP   1024         // candidate list capacity (== NT)

typedef float v4f __attribute__((ext_vector_type(4)));

__device__ __forceinline__ void load_row(const float* __restrict__ x,
                                         long long row, int tid,
                                         float4 v[VPT]) {
    const v4f* __restrict__ xr = (const v4f*)(x + row * NCOL);
#pragma unroll
    for (int j = 0; j < VPT; ++j) {
        const int q = tid + j * NT;
        if (j < VPT - 1 || q < NV4) {
            const v4f t = __builtin_nontemporal_load(&xr[q]);
            v[j] = make_float4(t.x, t.y, t.z, t.w);
        } else {
            v[j] = make_float4(-1e30f, -1e30f, -1e30f, -1e30f);
        }
    }
}

__device__ __forceinline__ void process_row(float* __restrict__ out,
                                            long long row, int tid, int lane,
                                            int wave, float4 v[VPT],
                                            float* __restrict__ sred,
                                            float* __restrict__ sS,
                                            int* __restrict__ sK,
                                            float* __restrict__ scand,
                                            int* __restrict__ scnt) {
    // init THIS parity's candidate buffer (other parity may still be read by
    // waves finishing the previous row's solve -- no conflict)
    scand[tid] = -1e30f;
    if (tid == 0) *scnt = 0;

    // ---- phase 1: row max ----
    float m = -1e30f;
#pragma unroll
    for (int j = 0; j < VPT; ++j)
        m = fmaxf(m, fmaxf(fmaxf(v[j].x, v[j].y), fmaxf(v[j].z, v[j].w)));
#pragma unroll
    for (int off = 32; off > 0; off >>= 1)
        m = fmaxf(m, __shfl_down(m, off, 64));
    if (lane == 0) sred[wave] = m;
    __syncthreads();                       // barrier A (covers init + sred)
    float M = sred[0];
#pragma unroll
    for (int w = 1; w < NWAVE; ++w) M = fmaxf(M, sred[w]);
    const float thr = M - 1.0f;            // support subset of {z > M-1}

    // ---- phase 2: gather candidates > thr ----
#pragma unroll
    for (int j = 0; j < VPT; ++j) {
        const float e0 = v[j].x, e1 = v[j].y, e2 = v[j].z, e3 = v[j].w;
        if (e0 > thr) { int p = atomicAdd(scnt, 1); if (p < CAP) scand[p] = e0; }
        if (e1 > thr) { int p = atomicAdd(scnt, 1); if (p < CAP) scand[p] = e1; }
        if (e2 > thr) { int p = atomicAdd(scnt, 1); if (p < CAP) scand[p] = e2; }
        if (e3 > thr) { int p = atomicAdd(scnt, 1); if (p < CAP) scand[p] = e3; }
    }
    __syncthreads();                       // barrier B
    const int cnt = *scnt;

    // ---- phase 3: tau via Michelot (redundant per wave, no barriers) ----
    float tau;
    if (cnt <= CAP) {
        float tau_l = thr;
        int kprev = -1;
        if (cnt <= 64) {
            const float cv = scand[lane];  // padded with -1e30
            for (int it = 0; it < 130; ++it) {
                float Sl = (cv > tau_l) ? cv : 0.0f;
                int   kl = (cv > tau_l) ? 1 : 0;
#pragma unroll
                for (int off = 32; off > 0; off >>= 1) {
                    Sl += __shfl_down(Sl, off, 64);
                    kl += __shfl_down(kl, off, 64);
                }
                const float St = __shfl(Sl, 0, 64);
                const int   kt = __shfl(kl, 0, 64);
                tau_l = (St - 1.0f) / (float)kt;
                if (kt == kprev) break;
                kprev = kt;
            }
        } else {
            const int cr = (cnt + 63) & ~63;
            for (int it = 0; it < CAP + 2; ++it) {
                float Sl = 0.0f; int kl = 0;
                for (int p = lane; p < cr; p += 64) {
                    const float e = scand[p];
                    if (e > tau_l) { Sl += e; kl++; }
                }
#pragma unroll
                for (int off = 32; off > 0; off >>= 1) {
                    Sl += __shfl_down(Sl, off, 64);
                    kl += __shfl_down(kl, off, 64);
                }
                const float St = __shfl(Sl, 0, 64);
                const int   kt = __shfl(kl, 0, 64);
                tau_l = (St - 1.0f) / (float)kt;
                if (kt == kprev) break;
                kprev = kt;
            }
        }
        tau = tau_l;
    } else {
        // pathological fallback: full-register Michelot, block reductions
        float tau_l = thr;
        int kprev = -1;
        for (int it = 0; it < 300; ++it) {
            float Sl = 0.0f; int kl = 0;
#pragma unroll
            for (int j = 0; j < VPT; ++j) {
                const float e0 = v[j].x, e1 = v[j].y, e2 = v[j].z, e3 = v[j].w;
                if (e0 > tau_l) { Sl += e0; kl++; }
                if (e1 > tau_l) { Sl += e1; kl++; }
                if (e2 > tau_l) { Sl += e2; kl++; }
                if (e3 > tau_l) { Sl += e3; kl++; }
            }
#pragma unroll
            for (int off = 32; off > 0; off >>= 1) {
                Sl += __shfl_down(Sl, off, 64);
                kl += __shfl_down(kl, off, 64);
            }
            if (lane == 0) { sS[wave] = Sl; sK[wave] = kl; }
            __syncthreads();
            float St = 0.0f; int kt = 0;
#pragma unroll
            for (int w = 0; w < NWAVE; ++w) { St += sS[w]; kt += sK[w]; }
            const float tnew = (St - 1.0f) / (float)kt;
            __syncthreads();
            tau_l = tnew;
            if (kt == kprev) break;
            kprev = kt;
        }
        tau = tau_l;
    }

    // ---- phase 4: write output (never re-read -> nt stores) ----
    v4f* __restrict__ outr = (v4f*)(out + row * NCOL);
#pragma unroll
    for (int j = 0; j < VPT; ++j) {
        const int q = tid + j * NT;
        if (j < VPT - 1 || q < NV4) {
            v4f o;
            o.x = fmaxf(v[j].x - tau, 0.0f);
            o.y = fmaxf(v[j].y - tau, 0.0f);
            o.z = fmaxf(v[j].z - tau, 0.0f);
            o.w = fmaxf(v[j].w - tau, 0.0f);
            __builtin_nontemporal_store(o, &outr[q]);
        }
    }
}

__global__ __launch_bounds__(NT, 4)
void sparsemax_kernel(const float* __restrict__ x, float* __restrict__ out,
                      int nrows, int rpb) {
    __shared__ float sred[NWAVE];
    __shared__ float sS[NWAVE];
    __shared__ int   sK[NWAVE];
    __shared__ float scand0[CAP];
    __shared__ float scand1[CAP];
    __shared__ int   scnt0;
    __shared__ int   scnt1;

    const int tid  = threadIdx.x;
    const int lane = tid & 63;
    const int wave = tid >> 6;

    const long long r0   = (long long)blockIdx.x * rpb;
    const long long rend = (r0 + rpb < nrows) ? (r0 + rpb) : nrows;
    if (r0 >= rend) return;

    float4 va[VPT], vb[VPT];

    // prologue: load first row
    load_row(x, r0, tid, va);

    long long r = r0;
    while (true) {
        // row r in va; prefetch r+1 into vb (in flight across the barriers)
        if (r + 1 < rend) load_row(x, r + 1, tid, vb);
        process_row(out, r, tid, lane, wave, va, sred, sS, sK, scand0, &scnt0);
        if (r + 1 >= rend) break;

        // row r+1 in vb; prefetch r+2 into va
        if (r + 2 < rend) load_row(x, r + 2, tid, va);
        process_row(out, r + 1, tid, lane, wave, vb, sred, sS, sK, scand1, &scnt1);
        if (r + 2 >= rend) break;
        r += 2;
    }
}

extern "C" void kernel_launch(void* const* d_in, const int* in_sizes, int n_in,
                              void* d_out, int out_size, void* d_ws, size_t ws_size,
                              hipStream_t stream) {
    const float* x = (const float*)d_in[0];
    float* out = (float*)d_out;
    const int rows = in_sizes[0] / NCOL;   // 4096
    const int nblocks = 256;               // 1 persistent block per CU
    const int rpb = (rows + nblocks - 1) / nblocks;   // 16
    sparsemax_kernel<<<nblocks, NT, 0, stream>>>(x, out, rows, rpb);
}